// Round 1
// baseline (227.062 us; speedup 1.0000x reference)
//
#include <hip/hip_runtime.h>
#include <hip/hip_bf16.h>

#define LLEN 4096
#define BATCH 16
#define NROWS 65536   // BATCH*LLEN
#define DDIM 128
#define JDIM 256      // 2*D
#define KM1 255       // K-1

union F4 { float4 v; float f[4]; };

__device__ __forceinline__ float clampf(float x, float lo, float hi) {
  return fminf(fmaxf(x, lo), hi);
}
__device__ __forceinline__ float tanh_fast(float x) {
  float e = __expf(2.0f * x);
  return 1.0f - 2.0f / (e + 1.0f);
}

// r[row] = X[row,:] . Wr   (one wave per row)
__global__ void kR(const float* __restrict__ X, const float* __restrict__ Wr,
                   float* __restrict__ rbuf) {
  const int lane = threadIdx.x & 63;
  const int wv   = threadIdx.x >> 6;
  const int row  = blockIdx.x * 4 + wv;
  const float2 x2 = *reinterpret_cast<const float2*>(X + (size_t)row * DDIM + lane * 2);
  const float2 w2 = *reinterpret_cast<const float2*>(Wr + lane * 2);
  float s = x2.x * w2.x + x2.y * w2.y;
  #pragma unroll
  for (int off = 32; off > 0; off >>= 1) s += __shfl_down(s, off, 64);
  if (lane == 0) rbuf[row] = s;
}

// t = tanh(X@W1 + b1), stored transpose-blocked: tT[rb][j][128], rb = row/128
__launch_bounds__(256, 2)
__global__ void kA(const float* __restrict__ X, const float* __restrict__ W1,
                   const float* __restrict__ b1, float* __restrict__ tT) {
  __shared__ float XT[16][128];
  __shared__ float W1c[16][256];
  const int tid = threadIdx.x;
  const int tr = tid & 15, tc = tid >> 4;
  const int rb = blockIdx.x;
  const size_t xbase = (size_t)rb * 128 * DDIM;

  float acc[2][4][16];
  #pragma unroll
  for (int a = 0; a < 2; ++a)
    #pragma unroll
    for (int b = 0; b < 4; ++b)
      #pragma unroll
      for (int c = 0; c < 16; ++c) acc[a][b][c] = 0.0f;

  for (int d0 = 0; d0 < DDIM; d0 += 16) {
    {
      const int row = tid >> 1;
      const int ds  = (tid & 1) * 8;
      const float* gp = X + xbase + (size_t)row * DDIM + d0 + ds;
      F4 v0, v1;
      v0.v = *reinterpret_cast<const float4*>(gp);
      v1.v = *reinterpret_cast<const float4*>(gp + 4);
      #pragma unroll
      for (int i = 0; i < 4; ++i) { XT[ds + i][row] = v0.f[i]; XT[ds + 4 + i][row] = v1.f[i]; }
    }
    #pragma unroll
    for (int q = 0; q < 4; ++q) {
      const int flat = q * 1024 + tid * 4;
      const int dd = flat >> 8, jj = flat & 255;
      *reinterpret_cast<float4*>(&W1c[dd][jj]) =
          *reinterpret_cast<const float4*>(W1 + (size_t)(d0 + dd) * JDIM + jj);
    }
    __syncthreads();
    #pragma unroll
    for (int dd = 0; dd < 16; ++dd) {
      F4 A0, A1, B0, B1, B2, B3;
      A0.v = *reinterpret_cast<const float4*>(&XT[dd][4 * tr]);
      A1.v = *reinterpret_cast<const float4*>(&XT[dd][64 + 4 * tr]);
      B0.v = *reinterpret_cast<const float4*>(&W1c[dd][4 * tc]);
      B1.v = *reinterpret_cast<const float4*>(&W1c[dd][64 + 4 * tc]);
      B2.v = *reinterpret_cast<const float4*>(&W1c[dd][128 + 4 * tc]);
      B3.v = *reinterpret_cast<const float4*>(&W1c[dd][192 + 4 * tc]);
      float av[8], wq[16];
      #pragma unroll
      for (int i = 0; i < 4; ++i) {
        av[i] = A0.f[i]; av[4 + i] = A1.f[i];
        wq[i] = B0.f[i]; wq[4 + i] = B1.f[i]; wq[8 + i] = B2.f[i]; wq[12 + i] = B3.f[i];
      }
      #pragma unroll
      for (int ri = 0; ri < 2; ++ri)
        #pragma unroll
        for (int ci = 0; ci < 4; ++ci)
          #pragma unroll
          for (int i = 0; i < 4; ++i)
            #pragma unroll
            for (int jj = 0; jj < 4; ++jj)
              acc[ri][ci][i * 4 + jj] += av[ri * 4 + i] * wq[ci * 4 + jj];
    }
    __syncthreads();
  }
  #pragma unroll
  for (int ci = 0; ci < 4; ++ci) {
    F4 bv; bv.v = *reinterpret_cast<const float4*>(b1 + ci * 64 + 4 * tc);
    #pragma unroll
    for (int ri = 0; ri < 2; ++ri) {
      #pragma unroll
      for (int jj = 0; jj < 4; ++jj) {
        const int j = ci * 64 + 4 * tc + jj;
        F4 o;
        #pragma unroll
        for (int i = 0; i < 4; ++i) o.f[i] = tanh_fast(acc[ri][ci][i * 4 + jj] + bv.f[jj]);
        *reinterpret_cast<float4*>(tT + ((size_t)rb * JDIM + j) * 128 + ri * 64 + 4 * tr) = o.v;
      }
    }
  }
}

// logits = tT^T @ W2 (reduce over j=256), masked exp, accumulate SumE / SumE*r per (b,k)
__launch_bounds__(256, 2)
__global__ void kB(const float* __restrict__ tT, const float* __restrict__ W2,
                   const float* __restrict__ mask, const float* __restrict__ rbuf,
                   float* __restrict__ Nsum, float* __restrict__ Dsum) {
  __shared__ float Tc[8][128];
  __shared__ float W2c[8][128];
  const int tid = threadIdx.x;
  const int tr = tid & 15, tc = tid >> 4;
  const int rc = blockIdx.x, kc = blockIdx.y, b = blockIdx.z;
  const int rb = b * 32 + rc;
  const size_t tbase = (size_t)rb * JDIM * 128;
  const int k0 = kc * 128;
  float acc[2][2][16];
  #pragma unroll
  for (int a = 0; a < 2; ++a)
    #pragma unroll
    for (int c = 0; c < 2; ++c)
      #pragma unroll
      for (int i = 0; i < 16; ++i) acc[a][c][i] = 0.0f;

  const int sj = tid >> 5;          // 0..7
  const int sr = (tid & 31) * 4;    // 0..124
  for (int j0 = 0; j0 < JDIM; j0 += 8) {
    *reinterpret_cast<float4*>(&Tc[sj][sr]) =
        *reinterpret_cast<const float4*>(tT + tbase + (size_t)(j0 + sj) * 128 + sr);
    {
      F4 wv;
      #pragma unroll
      for (int i = 0; i < 4; ++i) {
        const int kg = k0 + sr + i;
        wv.f[i] = (kg < KM1) ? W2[(size_t)(j0 + sj) * KM1 + kg] : 0.0f;
      }
      *reinterpret_cast<float4*>(&W2c[sj][sr]) = wv.v;
    }
    __syncthreads();
    #pragma unroll
    for (int jj = 0; jj < 8; ++jj) {
      F4 A0, A1, B0, B1;
      A0.v = *reinterpret_cast<const float4*>(&Tc[jj][4 * tr]);
      A1.v = *reinterpret_cast<const float4*>(&Tc[jj][64 + 4 * tr]);
      B0.v = *reinterpret_cast<const float4*>(&W2c[jj][4 * tc]);
      B1.v = *reinterpret_cast<const float4*>(&W2c[jj][64 + 4 * tc]);
      float av[8], wq[8];
      #pragma unroll
      for (int i = 0; i < 4; ++i) {
        av[i] = A0.f[i]; av[4 + i] = A1.f[i];
        wq[i] = B0.f[i]; wq[4 + i] = B1.f[i];
      }
      #pragma unroll
      for (int ri = 0; ri < 2; ++ri)
        #pragma unroll
        for (int ci = 0; ci < 2; ++ci)
          #pragma unroll
          for (int i = 0; i < 4; ++i)
            #pragma unroll
            for (int q = 0; q < 4; ++q)
              acc[ri][ci][i * 4 + q] += av[ri * 4 + i] * wq[ci * 4 + q];
    }
    __syncthreads();
  }
  float sE[8], sER[8];
  #pragma unroll
  for (int t = 0; t < 8; ++t) { sE[t] = 0.0f; sER[t] = 0.0f; }
  #pragma unroll
  for (int ri = 0; ri < 2; ++ri) {
    #pragma unroll
    for (int i = 0; i < 4; ++i) {
      const int row = rb * 128 + ri * 64 + 4 * tr + i;
      const float mv = mask[row];
      const float rv = rbuf[row];
      const float addm = (1.0f - mv) * (-1e30f);
      #pragma unroll
      for (int ci = 0; ci < 2; ++ci) {
        #pragma unroll
        for (int q = 0; q < 4; ++q) {
          const float e = __expf(mv * acc[ri][ci][i * 4 + q] + addm);
          sE[ci * 4 + q] += e;
          sER[ci * 4 + q] += e * rv;
        }
      }
    }
  }
  #pragma unroll
  for (int off = 1; off < 16; off <<= 1) {
    #pragma unroll
    for (int t = 0; t < 8; ++t) {
      sE[t] += __shfl_xor(sE[t], off, 64);
      sER[t] += __shfl_xor(sER[t], off, 64);
    }
  }
  if (tr == 0) {
    #pragma unroll
    for (int ci = 0; ci < 2; ++ci)
      #pragma unroll
      for (int q = 0; q < 4; ++q) {
        const int kg = k0 + ci * 64 + 4 * tc + q;
        if (kg < KM1) {
          atomicAdd(&Dsum[b * 256 + kg], sE[ci * 4 + q]);
          atomicAdd(&Nsum[b * 256 + kg], sER[ci * 4 + q]);
        }
      }
  }
}

// mu -> softmax -> cumsum -> modes -> cdf params (one block per b)
__global__ void kC(const float* __restrict__ Nsum, const float* __restrict__ Dsum,
                   const float* __restrict__ br, float* __restrict__ params) {
  __shared__ float red[256];
  __shared__ float sm[256];
  const int b = blockIdx.x;
  const int k = threadIdx.x;
  float v = 0.0f;
  if (k > 0) v = Nsum[b * 256 + (k - 1)] / Dsum[b * 256 + (k - 1)] + br[0];
  red[k] = v; __syncthreads();
  #pragma unroll
  for (int off = 128; off > 0; off >>= 1) {
    if (k < off) red[k] = fmaxf(red[k], red[k + off]);
    __syncthreads();
  }
  const float vmax = red[0];
  __syncthreads();
  const float e = expf(v - vmax);
  red[k] = e; __syncthreads();
  #pragma unroll
  for (int off = 128; off > 0; off >>= 1) {
    if (k < off) red[k] += red[k + off];
    __syncthreads();
  }
  const float tot = red[0];
  __syncthreads();
  sm[k] = e / tot; __syncthreads();
  for (int off = 1; off < 256; off <<= 1) {
    const float add = (k >= off) ? sm[k - off] : 0.0f;
    __syncthreads();
    sm[k] += add;
    __syncthreads();
  }
  if (k < KM1) {
    const float m  = clampf(sm[k], 1e-4f, 0.9999f);
    const float a  = clampf(m - 0.0625f, 0.0f, 0.875f);
    const float bb = clampf(a + 0.125f, 0.125f, 1.0f);
    const float ba = bb - a, ma = m - a, bm = bb - m;
    float* p = params + ((size_t)b * KM1 + k) * 8;
    *reinterpret_cast<float4*>(p)     = make_float4(m, a, bb, ma / ba);
    *reinterpret_cast<float4*>(p + 4) = make_float4(1.0f / ma, bm / ba, 1.0f / bm, 0.0f);
  }
}

// gamma_scaled + almat (fused): per (b, 256-l chunk)
__launch_bounds__(256)
__global__ void kD(const float* __restrict__ params, float* __restrict__ gamma,
                   float* __restrict__ almat) {
  __shared__ float P[KM1][8];
  __shared__ float gl[256];
  const int lc = blockIdx.x, b = blockIdx.y;
  const int tid = threadIdx.x;
  if (tid < KM1) {
    const float* p = params + ((size_t)b * KM1 + tid) * 8;
    *reinterpret_cast<float4*>(&P[tid][0]) = *reinterpret_cast<const float4*>(p);
    *reinterpret_cast<float4*>(&P[tid][4]) = *reinterpret_cast<const float4*>(p + 4);
  }
  __syncthreads();
  const int l = lc * 256 + tid;
  const float x = (float)l * (1.0f / 4095.0f);
  float g = 0.0f;
  for (int k = 0; k < KM1; ++k) {
    const float m = P[k][0], a = P[k][1], bb = P[k][2], cL = P[k][3];
    const float iMA = P[k][4], cR = P[k][5], iBM = P[k][6];
    float u = clampf((x - a) * iMA, 0.0f, 1.0f);
    u = u * u; u = u * u; u = u * u; u = u * u;
    float w = clampf((bb - x) * iBM, 0.0f, 1.0f);
    w = w * w; w = w * w; w = w * w; w = w * w;
    const float left  = cL * u;
    const float right = 1.0f - cR * w;
    g += (x <= m) ? left : right;
  }
  gamma[(size_t)b * LLEN + l] = g;
  gl[tid] = g;
  __syncthreads();
  const size_t base = ((size_t)b * LLEN + (size_t)lc * 256) * 256;
  for (int i = 0; i < 256; ++i) {
    const float gv = gl[i];
    const float val = fmaxf(1.0f - fabsf(gv - (float)tid), 0.0f);
    almat[base + (size_t)i * 256 + tid] = val;
  }
}

extern "C" void kernel_launch(void* const* d_in, const int* in_sizes, int n_in,
                              void* d_out, int out_size, void* d_ws, size_t ws_size,
                              hipStream_t stream) {
  const float* X    = (const float*)d_in[0];
  const float* mask = (const float*)d_in[1];
  const float* W1   = (const float*)d_in[2];
  const float* b1   = (const float*)d_in[3];
  const float* W2   = (const float*)d_in[4];
  const float* Wr   = (const float*)d_in[5];
  const float* br   = (const float*)d_in[6];
  float* out   = (float*)d_out;
  float* gamma = out;
  float* almat = out + NROWS;   // 65536 floats offset
  // scratch aliases inside d_out (fully overwritten by kD afterwards):
  float* tT   = almat;          // 16.7M floats: blocked t^T
  float* rbuf = gamma;          // 65536 floats: r = X.Wr
  float* Nsum = (float*)d_ws;                 // [16][256]
  float* Dsum = Nsum + BATCH * 256;           // [16][256]
  float* params = Dsum + BATCH * 256;         // [16][255][8]

  hipMemsetAsync(d_ws, 0, (size_t)BATCH * 256 * 2 * sizeof(float), stream);
  kR<<<NROWS / 4, 256, 0, stream>>>(X, Wr, rbuf);
  kA<<<NROWS / 128, 256, 0, stream>>>(X, W1, b1, tT);
  kB<<<dim3(32, 2, BATCH), 256, 0, stream>>>(tT, W2, mask, rbuf, Nsum, Dsum);
  kC<<<BATCH, 256, 0, stream>>>(Nsum, Dsum, br, params);
  kD<<<dim3(16, BATCH), 256, 0, stream>>>(params, gamma, almat);
}

// Round 2
// 144.630 us; speedup vs baseline: 1.5699x; 1.5699x over previous
//
#include <hip/hip_runtime.h>
#include <hip/hip_bf16.h>

#define LLEN 4096
#define BATCH 16
#define NROWS 65536   // BATCH*LLEN
#define DDIM 128
#define JDIM 256      // 2*D
#define KM1 255       // K-1

typedef __attribute__((ext_vector_type(8))) short s8v;   // bf16x8 MFMA frag (16B)
typedef __attribute__((ext_vector_type(4))) short s4v;   // half-frag (8B)
typedef __attribute__((ext_vector_type(8))) unsigned short us8; // 16B copy type
typedef __attribute__((ext_vector_type(4))) float f4v;   // MFMA acc

typedef unsigned short ushort_t;

__device__ __forceinline__ float clampf(float x, float lo, float hi) {
  return fminf(fmaxf(x, lo), hi);
}
__device__ __forceinline__ float tanh_fast(float x) {
  float e = __expf(2.0f * x);
  return 1.0f - 2.0f / (e + 1.0f);
}
__device__ __forceinline__ ushort_t bf16_rne(float x) {
  union { float f; unsigned u; } v; v.f = x;
  unsigned r = v.u + 0x7FFFu + ((v.u >> 16) & 1u);
  return (ushort_t)(r >> 16);
}
__device__ __forceinline__ float bf16_to_f(ushort_t h) {
  union { unsigned u; float f; } v; v.u = ((unsigned)h) << 16;
  return v.f;
}

// ---------------- prep: W1^T and W2^T hi/lo bf16 planes ----------------
__global__ void kW(const float* __restrict__ W1, const float* __restrict__ W2,
                   ushort_t* __restrict__ W1Th, ushort_t* __restrict__ W1Tl,
                   ushort_t* __restrict__ W2Th, ushort_t* __restrict__ W2Tl) {
  const int i0 = (blockIdx.x * 256 + threadIdx.x) * 4;
  #pragma unroll
  for (int t = 0; t < 4; ++t) {
    const int idx = i0 + t;
    if (idx < 32768) {                       // W1T[j][d] from W1[d][j]
      const int j = idx >> 7, d = idx & 127;
      const float v = W1[d * JDIM + j];
      const ushort_t h = bf16_rne(v);
      W1Th[idx] = h;
      W1Tl[idx] = bf16_rne(v - bf16_to_f(h));
    } else if (idx < 98304) {                // W2T[k][j] from W2[j][k], pad k=255
      const int i2 = idx - 32768;
      const int k = i2 >> 8, j = i2 & 255;
      const float v = (k < KM1) ? W2[j * KM1 + k] : 0.0f;
      const ushort_t h = bf16_rne(v);
      W2Th[i2] = h;
      W2Tl[i2] = bf16_rne(v - bf16_to_f(h));
    }
  }
}

// ---------------- kA: t = tanh(X@W1+b1) (MFMA, flipped: M=j, N=rows) ----------------
// Output t stored tiled: plane[( (rt*16 + jt)*64 + lane )*4 + reg], rt=row/16, jt=j/16.
// Also fused: rbuf[row] = X[row,:].Wr
__launch_bounds__(512, 2)
__global__ void kA(const float* __restrict__ X,
                   const ushort_t* __restrict__ W1Th, const ushort_t* __restrict__ W1Tl,
                   const float* __restrict__ b1, const float* __restrict__ Wr,
                   ushort_t* __restrict__ tHi, ushort_t* __restrict__ tLo,
                   float* __restrict__ rbuf) {
  const int tid  = threadIdx.x;
  const int lane = tid & 63, wid = tid >> 6;
  const int rr = lane & 15, g = lane >> 4;
  const int jw = wid & 3, rw = wid >> 2;
  const int j_base = jw * 64;
  const int r_base = blockIdx.x * 128 + rw * 64;

  f4v acc[4][4];
  #pragma unroll
  for (int m = 0; m < 4; ++m)
    #pragma unroll
    for (int n = 0; n < 4; ++n) { acc[m][n][0]=0.f; acc[m][n][1]=0.f; acc[m][n][2]=0.f; acc[m][n][3]=0.f; }
  float rp[4] = {0.f, 0.f, 0.f, 0.f};

  for (int ks = 0; ks < 4; ++ks) {
    const int d0 = ks * 32;
    // A-frags: W1T[j][d], lane: j = j_base+mf*16+rr, d = d0+8g+i (contig ushort8)
    s8v Ah[4], Al[4];
    #pragma unroll
    for (int mf = 0; mf < 4; ++mf) {
      const size_t o = (size_t)(j_base + mf * 16 + rr) * DDIM + d0 + 8 * g;
      Ah[mf] = *reinterpret_cast<const s8v*>(W1Th + o);
      Al[mf] = *reinterpret_cast<const s8v*>(W1Tl + o);
    }
    // Wr slice for fused r-dot
    float wr[8];
    {
      const float4 w0 = *reinterpret_cast<const float4*>(Wr + d0 + 8 * g);
      const float4 w1 = *reinterpret_cast<const float4*>(Wr + d0 + 8 * g + 4);
      wr[0]=w0.x; wr[1]=w0.y; wr[2]=w0.z; wr[3]=w0.w;
      wr[4]=w1.x; wr[5]=w1.y; wr[6]=w1.z; wr[7]=w1.w;
    }
    // B-frags: X rows (fp32 -> hi/lo on the fly), lane: col=r_base+nf*16+rr, k=d0+8g+i
    s8v Bh[4], Bl[4];
    #pragma unroll
    for (int nf = 0; nf < 4; ++nf) {
      const int r = r_base + nf * 16 + rr;
      const float* xp = X + (size_t)r * DDIM + d0 + 8 * g;
      const float4 x0 = *reinterpret_cast<const float4*>(xp);
      const float4 x1 = *reinterpret_cast<const float4*>(xp + 4);
      float xv[8] = {x0.x, x0.y, x0.z, x0.w, x1.x, x1.y, x1.z, x1.w};
      #pragma unroll
      for (int i = 0; i < 8; ++i) {
        const ushort_t h = bf16_rne(xv[i]);
        const float lo = xv[i] - bf16_to_f(h);
        Bh[nf][i] = (short)h;
        Bl[nf][i] = (short)bf16_rne(lo);
        rp[nf] += xv[i] * wr[i];
      }
    }
    // 3-term split MFMA
    #pragma unroll
    for (int mf = 0; mf < 4; ++mf)
      #pragma unroll
      for (int nf = 0; nf < 4; ++nf) {
        acc[mf][nf] = __builtin_amdgcn_mfma_f32_16x16x32_bf16(Ah[mf], Bh[nf], acc[mf][nf], 0, 0, 0);
        acc[mf][nf] = __builtin_amdgcn_mfma_f32_16x16x32_bf16(Ah[mf], Bl[nf], acc[mf][nf], 0, 0, 0);
        acc[mf][nf] = __builtin_amdgcn_mfma_f32_16x16x32_bf16(Al[mf], Bh[nf], acc[mf][nf], 0, 0, 0);
      }
  }
  // fused r: reduce over g (lanes ^16, ^32), rows depend on rr only
  #pragma unroll
  for (int nf = 0; nf < 4; ++nf) {
    rp[nf] += __shfl_xor(rp[nf], 16, 64);
    rp[nf] += __shfl_xor(rp[nf], 32, 64);
  }
  if (jw == 0 && lane < 16) {
    #pragma unroll
    for (int nf = 0; nf < 4; ++nf) rbuf[r_base + nf * 16 + lane] = rp[nf];
  }
  // epilogue: +b1, tanh, split hi/lo, tiled coalesced store
  #pragma unroll
  for (int mf = 0; mf < 4; ++mf) {
    const float4 bv = *reinterpret_cast<const float4*>(b1 + j_base + mf * 16 + 4 * g);
    const float bva[4] = {bv.x, bv.y, bv.z, bv.w};
    const int jt = (j_base + mf * 16) >> 4;
    #pragma unroll
    for (int nf = 0; nf < 4; ++nf) {
      const int rt = (r_base + nf * 16) >> 4;
      const size_t off = ((size_t)(rt * 16 + jt) * 64 + lane) * 4;
      s4v h4, l4;
      #pragma unroll
      for (int reg = 0; reg < 4; ++reg) {
        const float v = tanh_fast(acc[mf][nf][reg] + bva[reg]);
        const ushort_t h = bf16_rne(v);
        h4[reg] = (short)h;
        l4[reg] = (short)bf16_rne(v - bf16_to_f(h));
      }
      *reinterpret_cast<s4v*>(tHi + off) = h4;
      *reinterpret_cast<s4v*>(tLo + off) = l4;
    }
  }
}

// ---------------- kB: logits = t @ W2 (MFMA), masked exp, Nsum/Dsum atomics ----------------
__launch_bounds__(512, 2)
__global__ void kB(const ushort_t* __restrict__ tHi, const ushort_t* __restrict__ tLo,
                   const ushort_t* __restrict__ W2Th, const ushort_t* __restrict__ W2Tl,
                   const float* __restrict__ mask, const float* __restrict__ rbuf,
                   float* __restrict__ Nsum, float* __restrict__ Dsum) {
  __shared__ ushort_t W2s[2][256][40];   // [plane][k_out][j_local pad 40]
  const int tid  = threadIdx.x;
  const int lane = tid & 63, wid = tid >> 6;
  const int rr = lane & 15, g = lane >> 4;
  const int kw = wid & 3, rw = wid >> 2;
  const int k_base = kw * 64;
  const int r_base = blockIdx.x * 128 + rw * 64;
  const int b = blockIdx.x >> 5;         // 32 blocks per batch (128*32 = 4096 rows)

  f4v acc[4][4];
  #pragma unroll
  for (int m = 0; m < 4; ++m)
    #pragma unroll
    for (int n = 0; n < 4; ++n) { acc[m][n][0]=0.f; acc[m][n][1]=0.f; acc[m][n][2]=0.f; acc[m][n][3]=0.f; }

  for (int ks = 0; ks < 8; ++ks) {
    const int j0 = ks * 32;
    __syncthreads();
    // stage W2T slice [256 k][32 j] hi+lo
    #pragma unroll
    for (int c = 0; c < 4; ++c) {
      const int chunk = c * 512 + tid;          // 0..2047
      const int p = chunk >> 10, idx = chunk & 1023;
      const int kk = idx >> 2, jj = (idx & 3) * 8;
      const ushort_t* src = p ? W2Tl : W2Th;
      *reinterpret_cast<us8*>(&W2s[p][kk][jj]) =
          *reinterpret_cast<const us8*>(src + kk * 256 + j0 + jj);
    }
    __syncthreads();
    // A-frags from tiled t: lane needs k(=j) = j0 + 8g + i
    s8v Ah[4], Al[4];
    const int jt = (j0 >> 4) + (g >> 1);
    const int slot = 32 * (g & 1) + rr;
    #pragma unroll
    for (int mf = 0; mf < 4; ++mf) {
      const int rt = (r_base + mf * 16) >> 4;
      const size_t off = ((size_t)(rt * 16 + jt) * 64 + slot) * 4;
      const s4v h0 = *reinterpret_cast<const s4v*>(tHi + off);
      const s4v h1 = *reinterpret_cast<const s4v*>(tHi + off + 64);
      const s4v l0 = *reinterpret_cast<const s4v*>(tLo + off);
      const s4v l1 = *reinterpret_cast<const s4v*>(tLo + off + 64);
      #pragma unroll
      for (int i = 0; i < 4; ++i) {
        Ah[mf][i] = h0[i]; Ah[mf][4 + i] = h1[i];
        Al[mf][i] = l0[i]; Al[mf][4 + i] = l1[i];
      }
    }
    // B-frags from LDS: lane: col(k_out)=k_base+nf*16+rr, k(j)=8g+i
    s8v Bh[4], Bl[4];
    #pragma unroll
    for (int nf = 0; nf < 4; ++nf) {
      Bh[nf] = *reinterpret_cast<const s8v*>(&W2s[0][k_base + nf * 16 + rr][8 * g]);
      Bl[nf] = *reinterpret_cast<const s8v*>(&W2s[1][k_base + nf * 16 + rr][8 * g]);
    }
    #pragma unroll
    for (int mf = 0; mf < 4; ++mf)
      #pragma unroll
      for (int nf = 0; nf < 4; ++nf) {
        acc[mf][nf] = __builtin_amdgcn_mfma_f32_16x16x32_bf16(Ah[mf], Bh[nf], acc[mf][nf], 0, 0, 0);
        acc[mf][nf] = __builtin_amdgcn_mfma_f32_16x16x32_bf16(Ah[mf], Bl[nf], acc[mf][nf], 0, 0, 0);
        acc[mf][nf] = __builtin_amdgcn_mfma_f32_16x16x32_bf16(Al[mf], Bh[nf], acc[mf][nf], 0, 0, 0);
      }
  }
  // epilogue: e = exp(masked logit); accumulate per k over wave's 64 rows
  float sE[4] = {0.f,0.f,0.f,0.f}, sR[4] = {0.f,0.f,0.f,0.f};
  #pragma unroll
  for (int mf = 0; mf < 4; ++mf) {
    const int rloc = r_base + mf * 16 + 4 * g;
    #pragma unroll
    for (int reg = 0; reg < 4; ++reg) {
      const int row = rloc + reg;
      const float mv = mask[row];
      const float rv = rbuf[row];
      const float addm = (1.0f - mv) * (-1e30f);
      #pragma unroll
      for (int nf = 0; nf < 4; ++nf) {
        const float e = __expf(mv * acc[mf][nf][reg] + addm);
        sE[nf] += e;
        sR[nf] += e * rv;
      }
    }
  }
  #pragma unroll
  for (int nf = 0; nf < 4; ++nf) {
    sE[nf] += __shfl_xor(sE[nf], 16, 64);
    sE[nf] += __shfl_xor(sE[nf], 32, 64);
    sR[nf] += __shfl_xor(sR[nf], 16, 64);
    sR[nf] += __shfl_xor(sR[nf], 32, 64);
  }
  if (lane < 16) {
    #pragma unroll
    for (int nf = 0; nf < 4; ++nf) {
      const int kg = k_base + nf * 16 + lane;
      atomicAdd(&Dsum[b * 256 + kg], sE[nf]);
      atomicAdd(&Nsum[b * 256 + kg], sR[nf]);
    }
  }
}

// ---------------- kC: mu -> softmax -> cumsum -> cdf params (unchanged) ----------------
__global__ void kC(const float* __restrict__ Nsum, const float* __restrict__ Dsum,
                   const float* __restrict__ br, float* __restrict__ params) {
  __shared__ float red[256];
  __shared__ float sm[256];
  const int b = blockIdx.x;
  const int k = threadIdx.x;
  float v = 0.0f;
  if (k > 0) v = Nsum[b * 256 + (k - 1)] / Dsum[b * 256 + (k - 1)] + br[0];
  red[k] = v; __syncthreads();
  #pragma unroll
  for (int off = 128; off > 0; off >>= 1) {
    if (k < off) red[k] = fmaxf(red[k], red[k + off]);
    __syncthreads();
  }
  const float vmax = red[0];
  __syncthreads();
  const float e = expf(v - vmax);
  red[k] = e; __syncthreads();
  #pragma unroll
  for (int off = 128; off > 0; off >>= 1) {
    if (k < off) red[k] += red[k + off];
    __syncthreads();
  }
  const float tot = red[0];
  __syncthreads();
  sm[k] = e / tot; __syncthreads();
  for (int off = 1; off < 256; off <<= 1) {
    const float add = (k >= off) ? sm[k - off] : 0.0f;
    __syncthreads();
    sm[k] += add;
    __syncthreads();
  }
  if (k < KM1) {
    const float m  = clampf(sm[k], 1e-4f, 0.9999f);
    const float a  = clampf(m - 0.0625f, 0.0f, 0.875f);
    const float bb = clampf(a + 0.125f, 0.125f, 1.0f);
    const float ba = bb - a, ma = m - a, bm = bb - m;
    float* p = params + ((size_t)b * KM1 + k) * 8;
    *reinterpret_cast<float4*>(p)     = make_float4(m, a, bb, ma / ba);
    *reinterpret_cast<float4*>(p + 4) = make_float4(1.0f / ma, bm / ba, 1.0f / bm, 0.0f);
  }
}

// ---------------- kD: gamma_scaled + almat (unchanged) ----------------
__launch_bounds__(256)
__global__ void kD(const float* __restrict__ params, float* __restrict__ gamma,
                   float* __restrict__ almat) {
  __shared__ float P[KM1][8];
  __shared__ float gl[256];
  const int lc = blockIdx.x, b = blockIdx.y;
  const int tid = threadIdx.x;
  if (tid < KM1) {
    const float* p = params + ((size_t)b * KM1 + tid) * 8;
    *reinterpret_cast<float4*>(&P[tid][0]) = *reinterpret_cast<const float4*>(p);
    *reinterpret_cast<float4*>(&P[tid][4]) = *reinterpret_cast<const float4*>(p + 4);
  }
  __syncthreads();
  const int l = lc * 256 + tid;
  const float x = (float)l * (1.0f / 4095.0f);
  float g = 0.0f;
  for (int k = 0; k < KM1; ++k) {
    const float m = P[k][0], a = P[k][1], bb = P[k][2], cL = P[k][3];
    const float iMA = P[k][4], cR = P[k][5], iBM = P[k][6];
    float u = clampf((x - a) * iMA, 0.0f, 1.0f);
    u = u * u; u = u * u; u = u * u; u = u * u;
    float w = clampf((bb - x) * iBM, 0.0f, 1.0f);
    w = w * w; w = w * w; w = w * w; w = w * w;
    const float left  = cL * u;
    const float right = 1.0f - cR * w;
    g += (x <= m) ? left : right;
  }
  gamma[(size_t)b * LLEN + l] = g;
  gl[tid] = g;
  __syncthreads();
  const size_t base = ((size_t)b * LLEN + (size_t)lc * 256) * 256;
  for (int i = 0; i < 256; ++i) {
    const float gv = gl[i];
    const float val = fmaxf(1.0f - fabsf(gv - (float)tid), 0.0f);
    almat[base + (size_t)i * 256 + tid] = val;
  }
}

extern "C" void kernel_launch(void* const* d_in, const int* in_sizes, int n_in,
                              void* d_out, int out_size, void* d_ws, size_t ws_size,
                              hipStream_t stream) {
  const float* X    = (const float*)d_in[0];
  const float* mask = (const float*)d_in[1];
  const float* W1   = (const float*)d_in[2];
  const float* b1   = (const float*)d_in[3];
  const float* W2   = (const float*)d_in[4];
  const float* Wr   = (const float*)d_in[5];
  const float* br   = (const float*)d_in[6];
  float* out   = (float*)d_out;
  float* gamma = out;
  float* almat = out + NROWS;             // 65536 floats offset
  // scratch aliased inside d_out (fully overwritten later):
  float*    rbuf = gamma;                 // 65536 f32: r = X.Wr
  ushort_t* tHi  = (ushort_t*)almat;      // 16.7M bf16 hi plane (33.5 MB)
  ushort_t* tLo  = tHi + (size_t)NROWS * JDIM;  // lo plane (33.5 MB) — exact fit
  // workspace
  float* Nsum = (float*)d_ws;                    // [16][256]
  float* Dsum = Nsum + BATCH * 256;              // [16][256]
  float* params = Dsum + BATCH * 256;            // [16][255][8]
  ushort_t* W1Th = (ushort_t*)(params + (size_t)BATCH * KM1 * 8);
  ushort_t* W1Tl = W1Th + 32768;
  ushort_t* W2Th = W1Tl + 32768;
  ushort_t* W2Tl = W2Th + 65536;

  hipMemsetAsync(d_ws, 0, (size_t)BATCH * 256 * 2 * sizeof(float), stream);
  kW<<<96, 256, 0, stream>>>(W1, W2, W1Th, W1Tl, W2Th, W2Tl);
  kA<<<512, 512, 0, stream>>>(X, W1Th, W1Tl, b1, Wr, tHi, tLo, rbuf);
  kB<<<512, 512, 0, stream>>>(tHi, tLo, W2Th, W2Tl, mask, rbuf, Nsum, Dsum);
  kC<<<BATCH, 256, 0, stream>>>(Nsum, Dsum, br, params);
  kD<<<dim3(16, BATCH), 256, 0, stream>>>(params, gamma, almat);
}

// Round 3
// 110.059 us; speedup vs baseline: 2.0631x; 1.3141x over previous
//
#include <hip/hip_runtime.h>
#include <hip/hip_bf16.h>

#define LLEN 4096
#define BATCH 16
#define NROWS 65536   // BATCH*LLEN
#define DDIM 128
#define JDIM 256      // 2*D
#define KM1 255       // K-1
#define TPITCH 264    // t LDS pitch in halfs (pad 8)
#define SPITCH 40     // stage pitch in halfs (32 + pad 8)
#define LOSCALE 4096.0f
#define ILO (1.0f / 4096.0f)

typedef __attribute__((ext_vector_type(8))) _Float16 h8;
typedef __attribute__((ext_vector_type(4))) _Float16 h4;
typedef __attribute__((ext_vector_type(4))) float f4v;

__device__ __forceinline__ float clampf(float x, float lo, float hi) {
  return fminf(fmaxf(x, lo), hi);
}
__device__ __forceinline__ float tanh_fast(float x) {
  float e = __expf(2.0f * x);
  return 1.0f - 2.0f / (e + 1.0f);
}

// ---------------- kW: pack W1^T, W2^T into staged-slice fp16 hi/lo-scaled planes ----------------
// W1S[ks4][pl2][j256][dd32], W2S[ks8][pl2][k256][jj32]; lo plane pre-scaled by 4096.
__global__ void kW(const float* __restrict__ W1, const float* __restrict__ W2,
                   _Float16* __restrict__ W1S, _Float16* __restrict__ W2S) {
  const int t = blockIdx.x * 256 + threadIdx.x;
  if (t < 32768) {
    const int ks = t >> 13, rem = t & 8191, j = rem >> 5, dd = rem & 31;
    const float v = W1[(ks * 32 + dd) * JDIM + j];
    const _Float16 h = (_Float16)v;
    const float lo = (v - (float)h) * LOSCALE;
    W1S[(size_t)ks * 16384 + 0 * 8192 + j * 32 + dd] = h;
    W1S[(size_t)ks * 16384 + 1 * 8192 + j * 32 + dd] = (_Float16)lo;
  } else if (t < 98304) {
    const int t2 = t - 32768;
    const int ks = t2 >> 13, rem = t2 & 8191, k = rem >> 5, jj = rem & 31;
    const float v = (k < KM1) ? W2[(ks * 32 + jj) * KM1 + k] : 0.0f;
    const _Float16 h = (_Float16)v;
    const float lo = (v - (float)h) * LOSCALE;
    W2S[(size_t)ks * 16384 + 0 * 8192 + k * 32 + jj] = h;
    W2S[(size_t)ks * 16384 + 1 * 8192 + k * 32 + jj] = (_Float16)lo;
  }
}

// ---------------- kF: fused GEMM1(tanh) -> LDS t -> GEMM2 -> exp-sums ----------------
// block = 128 rows, 8 waves (mw = M-quarter, rw = row-half), per-wave 4x4 frags.
__launch_bounds__(512, 1)
__global__ void kF(const float* __restrict__ X,
                   const _Float16* __restrict__ W1S, const _Float16* __restrict__ W2S,
                   const float* __restrict__ b1, const float* __restrict__ Wr,
                   const float* __restrict__ mask,
                   float* __restrict__ Nsum, float* __restrict__ Dsum) {
  __shared__ _Float16 tS[128 * TPITCH];        // 67,584 B
  __shared__ _Float16 stg[2][2 * 256 * SPITCH]; // 2 x 40,960 B
  __shared__ float rS[128];

  const int tid  = threadIdx.x;
  const int lane = tid & 63, wid = tid >> 6;
  const int rr = lane & 15, g = lane >> 4;
  const int mw = wid & 3;        // M quarter (j in phase1, k in phase2)
  const int rw = wid >> 2;       // row half
  const int blk = blockIdx.x;
  const int b = blk >> 5;
  const int r_base = blk * 128;

  // staging mapping: each thread copies one 64B row-chunk (plane sm_pl, row sm_m)
  const int sm_pl = tid >> 8, sm_m = tid & 255;
  const size_t src_off = (size_t)sm_pl * 8192 + (size_t)sm_m * 32;
  _Float16* dst0 = &stg[0][(sm_pl * 256 + sm_m) * SPITCH];
  _Float16* dst1 = &stg[1][(sm_pl * 256 + sm_m) * SPITCH];

  f4v aH[4][4], aL[4][4];
  #pragma unroll
  for (int m = 0; m < 4; ++m)
    #pragma unroll
    for (int n = 0; n < 4; ++n) {
      aH[m][n][0]=0.f; aH[m][n][1]=0.f; aH[m][n][2]=0.f; aH[m][n][3]=0.f;
      aL[m][n][0]=0.f; aL[m][n][1]=0.f; aL[m][n][2]=0.f; aL[m][n][3]=0.f;
    }
  float rp[4] = {0.f, 0.f, 0.f, 0.f};

  // ---- phase 1: t = tanh(X@W1+b1), M=j(256), N=rows(128), K=d(128) ----
  {
    const h8* s0 = reinterpret_cast<const h8*>(W1S + src_off);
    h8* d = reinterpret_cast<h8*>(dst0);
    d[0]=s0[0]; d[1]=s0[1]; d[2]=s0[2]; d[3]=s0[3];
  }
  __syncthreads();
  for (int ks = 0; ks < 4; ++ks) {
    if (ks < 3) {
      const h8* s = reinterpret_cast<const h8*>(W1S + (size_t)(ks + 1) * 16384 + src_off);
      h8* d = reinterpret_cast<h8*>((ks & 1) ? dst0 : dst1);
      d[0]=s[0]; d[1]=s[1]; d[2]=s[2]; d[3]=s[3];
    }
    const _Float16* sb = stg[ks & 1];
    h8 Ah[4], Al[4];
    #pragma unroll
    for (int mf = 0; mf < 4; ++mf) {
      const int m = mw * 64 + mf * 16 + rr;
      Ah[mf] = *reinterpret_cast<const h8*>(&sb[(0 * 256 + m) * SPITCH + 8 * g]);
      Al[mf] = *reinterpret_cast<const h8*>(&sb[(1 * 256 + m) * SPITCH + 8 * g]);
    }
    float wr[8];
    {
      const float4 w0 = *reinterpret_cast<const float4*>(Wr + ks * 32 + 8 * g);
      const float4 w1 = *reinterpret_cast<const float4*>(Wr + ks * 32 + 8 * g + 4);
      wr[0]=w0.x; wr[1]=w0.y; wr[2]=w0.z; wr[3]=w0.w;
      wr[4]=w1.x; wr[5]=w1.y; wr[6]=w1.z; wr[7]=w1.w;
    }
    h8 Bx[4];
    #pragma unroll
    for (int nf = 0; nf < 4; ++nf) {
      const int r = r_base + rw * 64 + nf * 16 + rr;
      const float* xp = X + (size_t)r * DDIM + ks * 32 + 8 * g;
      const float4 x0 = *reinterpret_cast<const float4*>(xp);
      const float4 x1 = *reinterpret_cast<const float4*>(xp + 4);
      const float xv[8] = {x0.x, x0.y, x0.z, x0.w, x1.x, x1.y, x1.z, x1.w};
      #pragma unroll
      for (int i = 0; i < 8; ++i) Bx[nf][i] = (_Float16)xv[i];
      if (mw == 0) {
        #pragma unroll
        for (int i = 0; i < 8; ++i) rp[nf] += xv[i] * wr[i];
      }
    }
    #pragma unroll
    for (int mf = 0; mf < 4; ++mf)
      #pragma unroll
      for (int nf = 0; nf < 4; ++nf) {
        aH[mf][nf] = __builtin_amdgcn_mfma_f32_16x16x32_f16(Ah[mf], Bx[nf], aH[mf][nf], 0, 0, 0);
        aL[mf][nf] = __builtin_amdgcn_mfma_f32_16x16x32_f16(Al[mf], Bx[nf], aL[mf][nf], 0, 0, 0);
      }
    __syncthreads();
  }

  // epilogue 1: bias + tanh -> fp16 into tS; r-dot into rS
  #pragma unroll
  for (int mf = 0; mf < 4; ++mf) {
    const int j0 = mw * 64 + mf * 16 + 4 * g;
    const float4 bv = *reinterpret_cast<const float4*>(b1 + j0);
    const float bva[4] = {bv.x, bv.y, bv.z, bv.w};
    #pragma unroll
    for (int nf = 0; nf < 4; ++nf) {
      const int rl = rw * 64 + nf * 16 + rr;
      h4 o;
      #pragma unroll
      for (int reg = 0; reg < 4; ++reg) {
        const float v = tanh_fast(aH[mf][nf][reg] + aL[mf][nf][reg] * ILO + bva[reg]);
        o[reg] = (_Float16)v;
      }
      *reinterpret_cast<h4*>(&tS[rl * TPITCH + j0]) = o;
    }
  }
  if (mw == 0) {
    #pragma unroll
    for (int nf = 0; nf < 4; ++nf) {
      rp[nf] += __shfl_xor(rp[nf], 16, 64);
      rp[nf] += __shfl_xor(rp[nf], 32, 64);
    }
    if (g == 0) {
      #pragma unroll
      for (int nf = 0; nf < 4; ++nf) rS[rw * 64 + nf * 16 + rr] = rp[nf];
    }
  }
  // stage W2 slice 0 into buf0
  {
    const h8* s = reinterpret_cast<const h8*>(W2S + src_off);
    h8* d = reinterpret_cast<h8*>(dst0);
    d[0]=s[0]; d[1]=s[1]; d[2]=s[2]; d[3]=s[3];
  }
  // re-zero accumulators
  #pragma unroll
  for (int m = 0; m < 4; ++m)
    #pragma unroll
    for (int n = 0; n < 4; ++n) {
      aH[m][n][0]=0.f; aH[m][n][1]=0.f; aH[m][n][2]=0.f; aH[m][n][3]=0.f;
      aL[m][n][0]=0.f; aL[m][n][1]=0.f; aL[m][n][2]=0.f; aL[m][n][3]=0.f;
    }
  __syncthreads();

  // ---- phase 2: logits = t@W2, M=k(256), N=rows(128), K=j(256) ----
  for (int ks = 0; ks < 8; ++ks) {
    if (ks < 7) {
      const h8* s = reinterpret_cast<const h8*>(W2S + (size_t)(ks + 1) * 16384 + src_off);
      h8* d = reinterpret_cast<h8*>((ks & 1) ? dst0 : dst1);
      d[0]=s[0]; d[1]=s[1]; d[2]=s[2]; d[3]=s[3];
    }
    const _Float16* sb = stg[ks & 1];
    h8 Ah[4], Al[4], Bt[4];
    #pragma unroll
    for (int mf = 0; mf < 4; ++mf) {
      const int m = mw * 64 + mf * 16 + rr;
      Ah[mf] = *reinterpret_cast<const h8*>(&sb[(0 * 256 + m) * SPITCH + 8 * g]);
      Al[mf] = *reinterpret_cast<const h8*>(&sb[(1 * 256 + m) * SPITCH + 8 * g]);
    }
    #pragma unroll
    for (int nf = 0; nf < 4; ++nf) {
      const int rl = rw * 64 + nf * 16 + rr;
      Bt[nf] = *reinterpret_cast<const h8*>(&tS[rl * TPITCH + ks * 32 + 8 * g]);
    }
    #pragma unroll
    for (int mf = 0; mf < 4; ++mf)
      #pragma unroll
      for (int nf = 0; nf < 4; ++nf) {
        aH[mf][nf] = __builtin_amdgcn_mfma_f32_16x16x32_f16(Ah[mf], Bt[nf], aH[mf][nf], 0, 0, 0);
        aL[mf][nf] = __builtin_amdgcn_mfma_f32_16x16x32_f16(Al[mf], Bt[nf], aL[mf][nf], 0, 0, 0);
      }
    __syncthreads();
  }

  // epilogue 2: masked exp; per-k sums of e and e*r; atomics
  f4v sE[4], sR[4];
  #pragma unroll
  for (int mf = 0; mf < 4; ++mf) {
    sE[mf][0]=0.f; sE[mf][1]=0.f; sE[mf][2]=0.f; sE[mf][3]=0.f;
    sR[mf][0]=0.f; sR[mf][1]=0.f; sR[mf][2]=0.f; sR[mf][3]=0.f;
  }
  #pragma unroll
  for (int nf = 0; nf < 4; ++nf) {
    const int rl = rw * 64 + nf * 16 + rr;
    const int rg = r_base + rl;
    const float mv = mask[rg];
    const float rv = rS[rl];
    const float addm = (1.0f - mv) * (-1e30f);
    #pragma unroll
    for (int mf = 0; mf < 4; ++mf)
      #pragma unroll
      for (int reg = 0; reg < 4; ++reg) {
        const float logit = aH[mf][nf][reg] + aL[mf][nf][reg] * ILO;
        const float e = __expf(mv * logit + addm);
        sE[mf][reg] += e;
        sR[mf][reg] += e * rv;
      }
  }
  #pragma unroll
  for (int off = 1; off < 16; off <<= 1)
    #pragma unroll
    for (int mf = 0; mf < 4; ++mf)
      #pragma unroll
      for (int reg = 0; reg < 4; ++reg) {
        sE[mf][reg] += __shfl_xor(sE[mf][reg], off, 64);
        sR[mf][reg] += __shfl_xor(sR[mf][reg], off, 64);
      }
  if (rr == 0) {
    #pragma unroll
    for (int mf = 0; mf < 4; ++mf)
      #pragma unroll
      for (int reg = 0; reg < 4; ++reg) {
        const int k = mw * 64 + mf * 16 + 4 * g + reg;
        atomicAdd(&Dsum[b * 256 + k], sE[mf][reg]);
        atomicAdd(&Nsum[b * 256 + k], sR[mf][reg]);
      }
  }
}

// ---------------- kC: mu -> softmax -> cumsum -> cdf params ----------------
__global__ void kC(const float* __restrict__ Nsum, const float* __restrict__ Dsum,
                   const float* __restrict__ br, float* __restrict__ params) {
  __shared__ float red[256];
  __shared__ float sm[256];
  const int b = blockIdx.x;
  const int k = threadIdx.x;
  float v = 0.0f;
  if (k > 0) v = Nsum[b * 256 + (k - 1)] / Dsum[b * 256 + (k - 1)] + br[0];
  red[k] = v; __syncthreads();
  #pragma unroll
  for (int off = 128; off > 0; off >>= 1) {
    if (k < off) red[k] = fmaxf(red[k], red[k + off]);
    __syncthreads();
  }
  const float vmax = red[0];
  __syncthreads();
  const float e = expf(v - vmax);
  red[k] = e; __syncthreads();
  #pragma unroll
  for (int off = 128; off > 0; off >>= 1) {
    if (k < off) red[k] += red[k + off];
    __syncthreads();
  }
  const float tot = red[0];
  __syncthreads();
  sm[k] = e / tot; __syncthreads();
  for (int off = 1; off < 256; off <<= 1) {
    const float add = (k >= off) ? sm[k - off] : 0.0f;
    __syncthreads();
    sm[k] += add;
    __syncthreads();
  }
  if (k < KM1) {
    const float m  = clampf(sm[k], 1e-4f, 0.9999f);
    const float a  = clampf(m - 0.0625f, 0.0f, 0.875f);
    const float bb = clampf(a + 0.125f, 0.125f, 1.0f);
    const float ba = bb - a, ma = m - a, bm = bb - m;
    float* p = params + ((size_t)b * KM1 + k) * 8;
    *reinterpret_cast<float4*>(p)     = make_float4(m, a, bb, ma / ba);
    *reinterpret_cast<float4*>(p + 4) = make_float4(1.0f / ma, bm / ba, 1.0f / bm, 0.0f);
  }
}

// ---------------- kD: gamma_scaled + almat ----------------
__launch_bounds__(256)
__global__ void kD(const float* __restrict__ params, float* __restrict__ gamma,
                   float* __restrict__ almat) {
  __shared__ float P[KM1][8];
  __shared__ float gl[256];
  const int lc = blockIdx.x, b = blockIdx.y;
  const int tid = threadIdx.x;
  if (tid < KM1) {
    const float* p = params + ((size_t)b * KM1 + tid) * 8;
    *reinterpret_cast<float4*>(&P[tid][0]) = *reinterpret_cast<const float4*>(p);
    *reinterpret_cast<float4*>(&P[tid][4]) = *reinterpret_cast<const float4*>(p + 4);
  }
  __syncthreads();
  const int l = lc * 256 + tid;
  const float x = (float)l * (1.0f / 4095.0f);
  float g = 0.0f;
  for (int k = 0; k < KM1; ++k) {
    const float m = P[k][0], a = P[k][1], bb = P[k][2], cL = P[k][3];
    const float iMA = P[k][4], cR = P[k][5], iBM = P[k][6];
    float u = clampf((x - a) * iMA, 0.0f, 1.0f);
    u = u * u; u = u * u; u = u * u; u = u * u;
    float w = clampf((bb - x) * iBM, 0.0f, 1.0f);
    w = w * w; w = w * w; w = w * w; w = w * w;
    const float left  = cL * u;
    const float right = 1.0f - cR * w;
    g += (x <= m) ? left : right;
  }
  gamma[(size_t)b * LLEN + l] = g;
  gl[tid] = g;
  __syncthreads();
  const size_t base = ((size_t)b * LLEN + (size_t)lc * 256) * 256;
  for (int i = 0; i < 256; ++i) {
    const float gv = gl[i];
    const float val = fmaxf(1.0f - fabsf(gv - (float)tid), 0.0f);
    almat[base + (size_t)i * 256 + tid] = val;
  }
}

extern "C" void kernel_launch(void* const* d_in, const int* in_sizes, int n_in,
                              void* d_out, int out_size, void* d_ws, size_t ws_size,
                              hipStream_t stream) {
  const float* X    = (const float*)d_in[0];
  const float* mask = (const float*)d_in[1];
  const float* W1   = (const float*)d_in[2];
  const float* b1   = (const float*)d_in[3];
  const float* W2   = (const float*)d_in[4];
  const float* Wr   = (const float*)d_in[5];
  const float* br   = (const float*)d_in[6];
  float* out   = (float*)d_out;
  float* gamma = out;
  float* almat = out + NROWS;
  // workspace
  float* Nsum = (float*)d_ws;                        // [16][256]
  float* Dsum = Nsum + BATCH * 256;                  // [16][256]
  float* params = Dsum + BATCH * 256;                // [16][255][8]
  _Float16* W1S = (_Float16*)(params + (size_t)BATCH * KM1 * 8); // 65536 halfs
  _Float16* W2S = W1S + 65536;                                   // 131072 halfs

  hipMemsetAsync(d_ws, 0, (size_t)BATCH * 256 * 2 * sizeof(float), stream);
  kW<<<384, 256, 0, stream>>>(W1, W2, W1S, W2S);
  kF<<<512, 512, 0, stream>>>(X, W1S, W2S, b1, Wr, mask, Nsum, Dsum);
  kC<<<BATCH, 256, 0, stream>>>(Nsum, Dsum, br, params);
  kD<<<dim3(16, BATCH), 256, 0, stream>>>(params, gamma, almat);
}